// Round 29
// baseline (149.272 us; speedup 1.0000x reference)
//
#include <hip/hip_runtime.h>

#define B_   128
#define L_   196
#define ENC_ 2048
#define DEC_ 512
#define ATT_ 512
#define M_   (B_ * L_)   // 25088

typedef _Float16 f16x8 __attribute__((ext_vector_type(8)));
typedef __fp16   h16x2 __attribute__((ext_vector_type(2)));
typedef float    f32x4 __attribute__((ext_vector_type(4)));

// Raw barrier: order LDS ops (lgkmcnt) but do NOT drain vmcnt -> global
// prefetches stay in flight across the barrier.
#define FENCE_LDS_BARRIER()                                        \
    do {                                                           \
        asm volatile("s_waitcnt lgkmcnt(0)" ::: "memory");         \
        __builtin_amdgcn_s_barrier();                              \
        __builtin_amdgcn_sched_barrier(0);                         \
    } while (0)

// ---------------- ws layout ----------------
// [0,        262144)  dec_map f32 [128][512]
// [262144,  2359296)  WeTs    f16 tiled [nt=4][kt=64][k8=4][row=128] x f16x8
// [2359296, 2760704)  partial f32 [4][25088]

// We [2048][512] fp32 -> WeTs tiled-f16. Unit (nt,kt,k8,row) holds
// We[kt*32+k8*8+j][nt*128+row] for j=0..7.
__global__ void wets_kernel(const float* __restrict__ We, _Float16* __restrict__ WeTs) {
    int u = blockIdx.x * 256 + threadIdx.x;     // 131072 units
    int row = u & 127;
    int k8  = (u >> 7) & 3;
    int kt  = (u >> 9) & 63;
    int nt  = u >> 15;
    int n  = nt * 128 + row;
    int k0 = kt * 32 + k8 * 8;
    f16x8 h;
#pragma unroll
    for (int j = 0; j < 8; ++j) h[j] = (_Float16)We[(k0 + j) * ATT_ + n];
    *reinterpret_cast<f16x8*>(WeTs + (size_t)u * 8) = h;
}

// dec_map[b][a] = decoder_hidden[b] . Wd[:,a] + bd[a]
__global__ void decmap_kernel(const float* __restrict__ dh, const float* __restrict__ Wd,
                              const float* __restrict__ bd, float* __restrict__ dec) {
    int b = blockIdx.x;       // 128
    int a = threadIdx.x;      // 512
    float acc = bd[a];
    const float* dhp = dh + b * DEC_;
#pragma unroll 8
    for (int k = 0; k < DEC_; ++k) acc += dhp[k] * Wd[k * ATT_ + a];
    dec[b * ATT_ + a] = acc;
}

// Fused GEMM — R8's measured-fastest config (125-126us dispatch): 128x128
// tile, BK=32, 256 threads (4 waves 2x2, wave 64x64), grid 784 (mtile x 4
// ntiles, XCD-chunked), 3 blocks/CU. A: fp32->f16 reg staging, 2 static
// sets, 2-ahead, swizzled LDS dbuf; B: reg-staged f16 from pre-tiled WeTs;
// lgkm-only barriers (no vmcnt drain -> prefetches stay in flight).
// launch_bounds(256,3): 170-reg cap fits 64-acc + ~84 arch (measured, no
// spill). (256,4) caps at 128 -> catastrophic spill (R7/R10). DO NOT raise.
__global__ __launch_bounds__(256, 3)
void gemm_score_kernel(const float* __restrict__ enc,
                       const _Float16* __restrict__ WeTs,
                       const float* __restrict__ be,
                       const float* __restrict__ wa,
                       const float* __restrict__ dec,
                       float* __restrict__ partial) {
    __shared__ _Float16 smem[2][2][4096];
    __shared__ float red[2][128];

    // XCD-chunked swizzle: 4 ntile-siblings of one mtile stay on one XCD.
    int bid = blockIdx.x;
    int sid = (bid & 7) * 98 + (bid >> 3);           // bijective on [0,784)
    int mtile = sid >> 2;                            // 0..195
    int ntile = sid & 3;                             // 0..3

    int tid  = threadIdx.x;
    int lane = tid & 63, wid = tid >> 6;
    int wm = wid >> 1, wn = wid & 1;                 // 2x2 waves of 64x64
    int l15 = lane & 15, lg = lane >> 4;

    // A staging: thread -> (row = tid>>2 (+64), c8 = tid&3)
    int arowi = tid >> 2;                            // 0..63
    int ac8   = tid & 3;
    const float* agA = enc + (size_t)(mtile * 128 + arowi) * ENC_ + ac8 * 8;
    const float* agB = agA + (size_t)64 * ENC_;
    int wa0 = (ac8 * 128 + (arowi ^ (2 * ac8))) * 8;   // swizzled A unit
    int wa1 = wa0 + 64 * 8;

    // B staging: units tid, tid+256, linear.
    const _Float16* bbase = WeTs + (size_t)ntile * 64 * 4096;

    // frag read half-offsets
    int afo = (lg * 128 + wm * 64 + (l15 ^ (2 * lg))) * 8;   // A swizzled
    int bfo = (lg * 128 + wn * 64 + l15) * 8;                // B linear

    // 2-deep staging register sets — statically named (rule #20)
    float4 areg0[4], areg1[4];
    f16x8  breg0[2], breg1[2];

    f32x4 acc[4][4];
#pragma unroll
    for (int mi = 0; mi < 4; ++mi)
#pragma unroll
        for (int ni = 0; ni < 4; ++ni) acc[mi][ni] = (f32x4){0.f, 0.f, 0.f, 0.f};

    auto load0 = [&](int kt) {
        const float* a0 = agA + kt * 32;
        const float* a1 = agB + kt * 32;
        areg0[0] = *reinterpret_cast<const float4*>(a0);
        areg0[1] = *reinterpret_cast<const float4*>(a0 + 4);
        areg0[2] = *reinterpret_cast<const float4*>(a1);
        areg0[3] = *reinterpret_cast<const float4*>(a1 + 4);
        const _Float16* bs = bbase + (size_t)kt * 4096;
        breg0[0] = *reinterpret_cast<const f16x8*>(bs + tid * 8);
        breg0[1] = *reinterpret_cast<const f16x8*>(bs + (tid + 256) * 8);
    };
    auto load1 = [&](int kt) {
        const float* a0 = agA + kt * 32;
        const float* a1 = agB + kt * 32;
        areg1[0] = *reinterpret_cast<const float4*>(a0);
        areg1[1] = *reinterpret_cast<const float4*>(a0 + 4);
        areg1[2] = *reinterpret_cast<const float4*>(a1);
        areg1[3] = *reinterpret_cast<const float4*>(a1 + 4);
        const _Float16* bs = bbase + (size_t)kt * 4096;
        breg1[0] = *reinterpret_cast<const f16x8*>(bs + tid * 8);
        breg1[1] = *reinterpret_cast<const f16x8*>(bs + (tid + 256) * 8);
    };
    auto write0 = [&](int buf) {
        _Float16* As = smem[buf][0];
        _Float16* Bs = smem[buf][1];
        union { h16x2 h2[4]; f16x8 h8; } cv;
        cv.h2[0] = __builtin_amdgcn_cvt_pkrtz(areg0[0].x, areg0[0].y);
        cv.h2[1] = __builtin_amdgcn_cvt_pkrtz(areg0[0].z, areg0[0].w);
        cv.h2[2] = __builtin_amdgcn_cvt_pkrtz(areg0[1].x, areg0[1].y);
        cv.h2[3] = __builtin_amdgcn_cvt_pkrtz(areg0[1].z, areg0[1].w);
        *reinterpret_cast<f16x8*>(As + wa0) = cv.h8;
        cv.h2[0] = __builtin_amdgcn_cvt_pkrtz(areg0[2].x, areg0[2].y);
        cv.h2[1] = __builtin_amdgcn_cvt_pkrtz(areg0[2].z, areg0[2].w);
        cv.h2[2] = __builtin_amdgcn_cvt_pkrtz(areg0[3].x, areg0[3].y);
        cv.h2[3] = __builtin_amdgcn_cvt_pkrtz(areg0[3].z, areg0[3].w);
        *reinterpret_cast<f16x8*>(As + wa1) = cv.h8;
        *reinterpret_cast<f16x8*>(Bs + tid * 8) = breg0[0];
        *reinterpret_cast<f16x8*>(Bs + (tid + 256) * 8) = breg0[1];
    };
    auto write1 = [&](int buf) {
        _Float16* As = smem[buf][0];
        _Float16* Bs = smem[buf][1];
        union { h16x2 h2[4]; f16x8 h8; } cv;
        cv.h2[0] = __builtin_amdgcn_cvt_pkrtz(areg1[0].x, areg1[0].y);
        cv.h2[1] = __builtin_amdgcn_cvt_pkrtz(areg1[0].z, areg1[0].w);
        cv.h2[2] = __builtin_amdgcn_cvt_pkrtz(areg1[1].x, areg1[1].y);
        cv.h2[3] = __builtin_amdgcn_cvt_pkrtz(areg1[1].z, areg1[1].w);
        *reinterpret_cast<f16x8*>(As + wa0) = cv.h8;
        cv.h2[0] = __builtin_amdgcn_cvt_pkrtz(areg1[2].x, areg1[2].y);
        cv.h2[1] = __builtin_amdgcn_cvt_pkrtz(areg1[2].z, areg1[2].w);
        cv.h2[2] = __builtin_amdgcn_cvt_pkrtz(areg1[3].x, areg1[3].y);
        cv.h2[3] = __builtin_amdgcn_cvt_pkrtz(areg1[3].z, areg1[3].w);
        *reinterpret_cast<f16x8*>(As + wa1) = cv.h8;
        *reinterpret_cast<f16x8*>(Bs + tid * 8) = breg1[0];
        *reinterpret_cast<f16x8*>(Bs + (tid + 256) * 8) = breg1[1];
    };
    auto compute = [&](const _Float16* As, const _Float16* Bs) {
        f16x8 af[4], bf[4];
#pragma unroll
        for (int mi = 0; mi < 4; ++mi)
            af[mi] = *reinterpret_cast<const f16x8*>(As + afo + mi * 128);
#pragma unroll
        for (int ni = 0; ni < 4; ++ni)
            bf[ni] = *reinterpret_cast<const f16x8*>(Bs + bfo + ni * 128);
#pragma unroll
        for (int mi = 0; mi < 4; ++mi)
#pragma unroll
            for (int ni = 0; ni < 4; ++ni)
                acc[mi][ni] = __builtin_amdgcn_mfma_f32_16x16x32_f16(
                    af[mi], bf[ni], acc[mi][ni], 0, 0, 0);
    };

    load0(0);
    load1(1);
    write0(0);
    FENCE_LDS_BARRIER();

    for (int kt2 = 0; kt2 < 32; ++kt2) {
        int kt = kt2 * 2;
        if (kt2 < 31) load0(kt + 2);
        compute(smem[0][0], smem[0][1]);
        write1(1);
        FENCE_LDS_BARRIER();
        if (kt2 < 31) load1(kt + 3);
        compute(smem[1][0], smem[1][1]);
        if (kt2 < 31) write0(0);
        FENCE_LDS_BARRIER();
    }

    // Epilogue: x = acc + be[n] + dec[b][n]; rowsum += tanh(x)*wa[n]
    float rsum[4][4];
#pragma unroll
    for (int mi = 0; mi < 4; ++mi)
#pragma unroll
        for (int j = 0; j < 4; ++j) rsum[mi][j] = 0.f;

    int nb = ntile * 128 + wn * 64;
    int rb = mtile * 128 + wm * 64;
#pragma unroll
    for (int ni = 0; ni < 4; ++ni) {
        int n = nb + ni * 16 + l15;
        float wav = wa[n];
        float bev = be[n];
#pragma unroll
        for (int mi = 0; mi < 4; ++mi) {
#pragma unroll
            for (int j = 0; j < 4; ++j) {
                int row = rb + mi * 16 + lg * 4 + j;    // C/D: col=lane&15, row=(lane>>4)*4+reg
                int b = row / L_;
                float x = acc[mi][ni][j] + bev + dec[b * ATT_ + n];
                float e = __expf(2.0f * x);
                float t = 1.0f - 2.0f / (e + 1.0f);     // tanh(x), inf-safe
                rsum[mi][j] += t * wav;
            }
        }
    }
#pragma unroll
    for (int mi = 0; mi < 4; ++mi) {
#pragma unroll
        for (int j = 0; j < 4; ++j) {
            float v = rsum[mi][j];
            v += __shfl_xor(v, 1);
            v += __shfl_xor(v, 2);
            v += __shfl_xor(v, 4);
            v += __shfl_xor(v, 8);
            if (l15 == 0) red[wn][wm * 64 + mi * 16 + lg * 4 + j] = v;
        }
    }
    __syncthreads();
    if (tid < 128)
        partial[(size_t)ntile * M_ + mtile * 128 + tid] = red[0][tid] + red[1][tid];
}

// softmax over L per batch row; sums the 4 ntile partials. ba cancels.
__global__ void softmax_kernel(const float* __restrict__ partial, float* __restrict__ alphas) {
    int b = blockIdx.x, t = threadIdx.x;     // 128 blocks x 256 threads
    int lane = t & 63, wid = t >> 6;
    __shared__ float red[4];
    float s = 0.f, val = -1e30f;
    if (t < L_) {
        int r = b * L_ + t;
        s = partial[r] + partial[M_ + r] + partial[2 * M_ + r] + partial[3 * M_ + r];
        val = s;
    }
    float m = val;
#pragma unroll
    for (int off = 1; off < 64; off <<= 1) m = fmaxf(m, __shfl_xor(m, off));
    if (lane == 0) red[wid] = m;
    __syncthreads();
    m = fmaxf(fmaxf(red[0], red[1]), fmaxf(red[2], red[3]));
    float e = (t < L_) ? __expf(s - m) : 0.f;
    float sum = e;
#pragma unroll
    for (int off = 1; off < 64; off <<= 1) sum += __shfl_xor(sum, off);
    __syncthreads();
    if (lane == 0) red[wid] = sum;
    __syncthreads();
    sum = red[0] + red[1] + red[2] + red[3];
    if (t < L_) alphas[b * L_ + t] = e / sum;
}

// context[b][e] = sum_l alphas[b][l] * enc[b][l][e]  (float4 loads, G13)
__global__ void context_kernel(const float* __restrict__ enc, const float* __restrict__ alphas,
                               float* __restrict__ ctx) {
    int b = blockIdx.x >> 1;                  // 128 b x 2 e-chunks = 256 blocks
    int ec = blockIdx.x & 1;
    int e = ec * 1024 + threadIdx.x * 4;
    const float* ep = enc + (size_t)b * L_ * ENC_ + e;
    const float* ap = alphas + b * L_;
    float a0 = 0.f, a1 = 0.f, a2 = 0.f, a3 = 0.f;
#pragma unroll 4
    for (int l = 0; l < L_; ++l) {
        float a = ap[l];
        float4 v = *reinterpret_cast<const float4*>(ep + (size_t)l * ENC_);
        a0 += a * v.x;
        a1 += a * v.y;
        a2 += a * v.z;
        a3 += a * v.w;
    }
    float4 r; r.x = a0; r.y = a1; r.z = a2; r.w = a3;
    *reinterpret_cast<float4*>(&ctx[b * ENC_ + e]) = r;
}

extern "C" void kernel_launch(void* const* d_in, const int* in_sizes, int n_in,
                              void* d_out, int out_size, void* d_ws, size_t ws_size,
                              hipStream_t stream) {
    const float* enc = (const float*)d_in[0];
    const float* dh  = (const float*)d_in[1];
    const float* We  = (const float*)d_in[2];
    const float* be  = (const float*)d_in[3];
    const float* Wd  = (const float*)d_in[4];
    const float* bd  = (const float*)d_in[5];
    const float* wa  = (const float*)d_in[6];
    // d_in[7] = ba: shifts all scores equally -> cancels in softmax, unused.

    float* out    = (float*)d_out;
    float* ctx    = out;               // [128][2048]
    float* alphas = out + B_ * ENC_;   // [128][196]

    char* ws = (char*)d_ws;
    float*    dec     = (float*)ws;                            // 256 KiB
    _Float16* WeTs    = (_Float16*)(ws + 262144);              // 2 MiB
    float*    partial = (float*)(ws + 2359296);                // 392 KiB

    hipLaunchKernelGGL(wets_kernel,       dim3(512), dim3(256), 0, stream, We, WeTs);
    hipLaunchKernelGGL(decmap_kernel,     dim3(128), dim3(512), 0, stream, dh, Wd, bd, dec);
    hipLaunchKernelGGL(gemm_score_kernel, dim3(784), dim3(256), 0, stream, enc, WeTs, be, wa, dec, partial);
    hipLaunchKernelGGL(softmax_kernel,    dim3(128), dim3(256), 0, stream, partial, alphas);
    hipLaunchKernelGGL(context_kernel,    dim3(256), dim3(256), 0, stream, enc, alphas, ctx);
}